// Round 2
// 486.184 us; speedup vs baseline: 1.0137x; 1.0137x over previous
//
#include <hip/hip_runtime.h>
#include <math.h>

// Problem constants (fixed by setup_inputs)
#define B_   64
#define N_   16384
#define C_   64
#define S_   16                    // N-splits for partial stats
#define ROWS_PER_BLK (N_ / S_)     // 1024 rows of C_ floats per stats block
#define EPS_ 1e-6f
#define ALPHA_MAX_ 0.5f

// clang native vector type — required by __builtin_nontemporal_store
// (HIP's float4 is a class and is rejected). Same 16B layout.
typedef float fvec4 __attribute__((ext_vector_type(4)));

// ---------------------------------------------------------------------------
// Kernel 1: per-(b, channel) partial sum / sumsq over an N-slice.
// Grid: B_*S_ blocks of 256 threads. Each wave reads a contiguous 1 KB
// (float4 per lane), so loads are perfectly coalesced. Regular (caching)
// loads on purpose: this pass pulls x into the 256 MiB Infinity Cache so
// the apply pass can re-read it from L3 instead of HBM.
// ---------------------------------------------------------------------------
__global__ __launch_bounds__(256) void stats_partial_kernel(
    const float* __restrict__ x,
    float* __restrict__ sumP,   // [B_*S_][C_]
    float* __restrict__ sqP)    // [B_*S_][C_]
{
    const int bid = blockIdx.x;        // = b*S_ + s
    const int b   = bid >> 4;          // /S_ (S_==16)
    const int s   = bid & 15;

    const float4* xp = (const float4*)(x + ((size_t)b * N_ + (size_t)s * ROWS_PER_BLK) * C_);

    const int tid  = threadIdx.x;
    const int cg   = tid & 15;         // channel-group: covers channels cg*4..cg*4+3
    const int row0 = tid >> 4;         // 0..15

    float4 sum = make_float4(0.f, 0.f, 0.f, 0.f);
    float4 sq  = make_float4(0.f, 0.f, 0.f, 0.f);

    // Each row has C_/4 = 16 float4s; thread walks rows with stride 16.
    for (int r = row0; r < ROWS_PER_BLK; r += 16) {
        float4 v = xp[r * 16 + cg];
        sum.x += v.x; sum.y += v.y; sum.z += v.z; sum.w += v.w;
        sq.x  += v.x * v.x; sq.y += v.y * v.y; sq.z += v.z * v.z; sq.w += v.w * v.w;
    }

    __shared__ float lds[256][8];
    lds[tid][0] = sum.x; lds[tid][1] = sum.y; lds[tid][2] = sum.z; lds[tid][3] = sum.w;
    lds[tid][4] = sq.x;  lds[tid][5] = sq.y;  lds[tid][6] = sq.z;  lds[tid][7] = sq.w;
    __syncthreads();

    // Reduce across the 16 row-threads sharing each channel-group.
    // tid layout = row0*16 + cg, so strides of 16 preserve cg.
    for (int off = 128; off >= 16; off >>= 1) {
        if (tid < off) {
            #pragma unroll
            for (int k = 0; k < 8; ++k) lds[tid][k] += lds[tid + off][k];
        }
        __syncthreads();
    }

    if (tid < 16) {
        float* sp = sumP + (size_t)bid * C_ + tid * 4;
        float* qp = sqP  + (size_t)bid * C_ + tid * 4;
        sp[0] = lds[tid][0]; sp[1] = lds[tid][1]; sp[2] = lds[tid][2]; sp[3] = lds[tid][3];
        qp[0] = lds[tid][4]; qp[1] = lds[tid][5]; qp[2] = lds[tid][6]; qp[3] = lds[tid][7];
    }
}

// ---------------------------------------------------------------------------
// Kernel 2: finalize stats, compute mixing partner, emit per-(b,c) scale/bias.
// 4096 threads total. Partner argmax recomputed per thread (trivial work, all
// label/noise data is L2-resident). Touches only ~550 KB, so it barely
// perturbs the L3-resident copy of x between pass 1 and pass 3.
// ---------------------------------------------------------------------------
__global__ __launch_bounds__(256) void scale_bias_kernel(
    const float* __restrict__ sumP,
    const float* __restrict__ sqP,
    const float* __restrict__ alpha_u,      // [B_]
    const float* __restrict__ select_noise, // [B_][B_]
    const int*   __restrict__ dom,          // [B_]
    const int*   __restrict__ cls,          // [B_]
    float* __restrict__ scaleArr,           // [B_][C_]
    float* __restrict__ biasArr)            // [B_][C_]
{
    const int t = blockIdx.x * blockDim.x + threadIdx.x;  // 0..4095
    const int b = t >> 6;
    const int c = t & 63;

    // argmax over valid partners (first occurrence on ties, like jnp.argmax)
    const int myCls = cls[b];
    const int myDom = dom[b];
    float best = -1.0f;   // noise is uniform[0,1), so any valid score beats -1
    int   bi   = -1;
    for (int j = 0; j < B_; ++j) {
        if (cls[j] == myCls && dom[j] != myDom) {
            float sc = select_noise[b * B_ + j];
            if (sc > best) { best = sc; bi = j; }
        }
    }
    const int idx = (bi < 0) ? b : bi;

    // Reduce S_ partials for self and partner in double.
    double sum = 0.0, sq = 0.0, sum2 = 0.0, sq2 = 0.0;
    for (int s = 0; s < S_; ++s) {
        sum  += (double)sumP[((size_t)b   * S_ + s) * C_ + c];
        sq   += (double)sqP [((size_t)b   * S_ + s) * C_ + c];
        sum2 += (double)sumP[((size_t)idx * S_ + s) * C_ + c];
        sq2  += (double)sqP [((size_t)idx * S_ + s) * C_ + c];
    }

    const double n = (double)N_;
    const double mu_d   = sum  / n;
    const double var_d  = (sq  - sum  * sum  / n) / (n - 1.0);
    const double mu2_d  = sum2 / n;
    const double var2_d = (sq2 - sum2 * sum2 / n) / (n - 1.0);

    const float mu   = (float)mu_d;
    const float sig  = sqrtf((float)var_d  + EPS_);
    const float mu2  = (float)mu2_d;
    const float sig2 = sqrtf((float)var2_d + EPS_);

    const float a = alpha_u[b] * ALPHA_MAX_;
    const float mu_mix  = mu  * a + mu2  * (1.0f - a);
    const float sig_mix = sig * a + sig2 * (1.0f - a);

    const float scale = sig_mix / sig;
    scaleArr[t] = scale;
    biasArr[t]  = mu_mix - mu * scale;
}

// ---------------------------------------------------------------------------
// Kernel 3: out = x * scale[b,c] + bias[b,c].
// 2048 blocks x 256 threads; 32 blocks per sample, each block owns a
// contiguous 128 KB chunk (8192 float4). b is block-uniform and the channel
// group is thread-constant, so scale/bias are loaded exactly once per thread.
// Output is written with NON-TEMPORAL stores so the write stream does not
// allocate in L2/L3 — keeping x (loaded by pass 1, exactly L3-sized)
// resident in Infinity Cache for this pass's read stream. Expected effect:
// apply's x reads become L3 hits, kernel becomes HBM-write-bound.
// ---------------------------------------------------------------------------
__global__ __launch_bounds__(256) void apply_kernel(
    const float* __restrict__ x,
    const float* __restrict__ scaleArr,
    const float* __restrict__ biasArr,
    float* __restrict__ out)
{
    const int b  = blockIdx.x >> 5;          // 32 blocks per sample
    const int cg = threadIdx.x & 15;         // channel-group within a row (256 % 16 == 0)

    const float4 sc = ((const float4*)scaleArr)[b * 16 + cg];
    const float4 bs = ((const float4*)biasArr)[b * 16 + cg];

    const size_t base = (size_t)blockIdx.x * 8192 + threadIdx.x;  // float4 index
    const float4* __restrict__ xin = (const float4*)x;
    fvec4* __restrict__ op = (fvec4*)out;

    #pragma unroll 4
    for (int it = 0; it < 32; ++it) {
        const size_t g = base + (size_t)it * 256;
        float4 v = xin[g];
        fvec4 o;
        o.x = fmaf(v.x, sc.x, bs.x);
        o.y = fmaf(v.y, sc.y, bs.y);
        o.z = fmaf(v.z, sc.z, bs.z);
        o.w = fmaf(v.w, sc.w, bs.w);
        __builtin_nontemporal_store(o, op + g);
    }
}

// ---------------------------------------------------------------------------
extern "C" void kernel_launch(void* const* d_in, const int* in_sizes, int n_in,
                              void* d_out, int out_size, void* d_ws, size_t ws_size,
                              hipStream_t stream) {
    const float* x            = (const float*)d_in[0];
    const float* alpha_u      = (const float*)d_in[1];
    const float* select_noise = (const float*)d_in[2];
    const int*   dom          = (const int*)d_in[3];
    const int*   cls          = (const int*)d_in[4];
    float* out = (float*)d_out;

    // Workspace layout (floats): sumP[B_*S_*C_], sqP[B_*S_*C_], scale[B_*C_], bias[B_*C_]
    float* sumP     = (float*)d_ws;
    float* sqP      = sumP + (size_t)B_ * S_ * C_;          // +65536
    float* scaleArr = sqP  + (size_t)B_ * S_ * C_;          // +65536
    float* biasArr  = scaleArr + (size_t)B_ * C_;           // +4096

    // 1) partial stats: 1024 blocks x 256 threads (pulls x into L3)
    stats_partial_kernel<<<B_ * S_, 256, 0, stream>>>(x, sumP, sqP);

    // 2) finalize + mixing: 4096 threads
    scale_bias_kernel<<<(B_ * C_) / 256, 256, 0, stream>>>(
        sumP, sqP, alpha_u, select_noise, dom, cls, scaleArr, biasArr);

    // 3) apply: 2048 blocks, 32 float4/thread, nt stores
    apply_kernel<<<2048, 256, 0, stream>>>(x, scaleArr, biasArr, out);
}

// Round 4
// 484.177 us; speedup vs baseline: 1.0179x; 1.0041x over previous
//
#include <hip/hip_runtime.h>
#include <math.h>

// Problem constants (fixed by setup_inputs)
#define B_   64
#define N_   16384
#define C_   64
#define S_   16                    // N-splits for partial stats
#define ROWS_PER_BLK (N_ / S_)     // 1024 rows of C_ floats per stats block
#define EPS_ 1e-6f
#define ALPHA_MAX_ 0.5f

// clang native vector type — required by __builtin_nontemporal_store
typedef float fvec4 __attribute__((ext_vector_type(4)));

// ---------------------------------------------------------------------------
// Kernel 1: per-(b, channel) partial sum / sumsq over an N-slice.
// Grid: B_*S_ blocks of 256 threads. Each wave reads a contiguous 1 KB
// (float4 per lane), so loads are perfectly coalesced. (Proven, unchanged.)
// ---------------------------------------------------------------------------
__global__ __launch_bounds__(256) void stats_partial_kernel(
    const float* __restrict__ x,
    float* __restrict__ sumP,   // [B_*S_][C_]
    float* __restrict__ sqP)    // [B_*S_][C_]
{
    const int bid = blockIdx.x;        // = b*S_ + s
    const int b   = bid >> 4;          // /S_ (S_==16)
    const int s   = bid & 15;

    const float4* xp = (const float4*)(x + ((size_t)b * N_ + (size_t)s * ROWS_PER_BLK) * C_);

    const int tid  = threadIdx.x;
    const int cg   = tid & 15;         // channel-group: covers channels cg*4..cg*4+3
    const int row0 = tid >> 4;         // 0..15

    float4 sum = make_float4(0.f, 0.f, 0.f, 0.f);
    float4 sq  = make_float4(0.f, 0.f, 0.f, 0.f);

    // Each row has C_/4 = 16 float4s; thread walks rows with stride 16.
    #pragma unroll 8
    for (int r = row0; r < ROWS_PER_BLK; r += 16) {
        float4 v = xp[r * 16 + cg];
        sum.x += v.x; sum.y += v.y; sum.z += v.z; sum.w += v.w;
        sq.x = fmaf(v.x, v.x, sq.x); sq.y = fmaf(v.y, v.y, sq.y);
        sq.z = fmaf(v.z, v.z, sq.z); sq.w = fmaf(v.w, v.w, sq.w);
    }

    __shared__ float lds[256][8];
    lds[tid][0] = sum.x; lds[tid][1] = sum.y; lds[tid][2] = sum.z; lds[tid][3] = sum.w;
    lds[tid][4] = sq.x;  lds[tid][5] = sq.y;  lds[tid][6] = sq.z;  lds[tid][7] = sq.w;
    __syncthreads();

    // Reduce across the 16 row-threads sharing each channel-group.
    // tid layout = row0*16 + cg, so strides of 16 preserve cg.
    for (int off = 128; off >= 16; off >>= 1) {
        if (tid < off) {
            #pragma unroll
            for (int k = 0; k < 8; ++k) lds[tid][k] += lds[tid + off][k];
        }
        __syncthreads();
    }

    if (tid < 16) {
        float* sp = sumP + (size_t)bid * C_ + tid * 4;
        float* qp = sqP  + (size_t)bid * C_ + tid * 4;
        sp[0] = lds[tid][0]; sp[1] = lds[tid][1]; sp[2] = lds[tid][2]; sp[3] = lds[tid][3];
        qp[0] = lds[tid][4]; qp[1] = lds[tid][5]; qp[2] = lds[tid][6]; qp[3] = lds[tid][7];
    }
}

// ---------------------------------------------------------------------------
// Kernel 2 (fused finalize + apply): each block owns a contiguous 128 KB
// chunk of one sample. Threads 0..63 recompute that sample's scale/bias from
// the partials (argmax is block-uniform scalar work; the 16 KiB of partials
// is L2-resident — duplicated across the 32 blocks per sample but fully
// parallel and hidden under the x prefetch issued first). Saves the separate
// scale_bias dispatch + one graph-node gap.
// ---------------------------------------------------------------------------
#define PRE 8                      // float4 prefetched per thread before scb
__global__ __launch_bounds__(256) void apply_fused_kernel(
    const float* __restrict__ x,
    const float* __restrict__ sumP,
    const float* __restrict__ sqP,
    const float* __restrict__ alpha_u,      // [B_]
    const float* __restrict__ select_noise, // [B_][B_]
    const int*   __restrict__ dom,          // [B_]
    const int*   __restrict__ cls,          // [B_]
    float* __restrict__ out)
{
    const int tid = threadIdx.x;
    const int b   = blockIdx.x >> 5;          // 32 blocks per sample

    const size_t base = (size_t)blockIdx.x * 8192 + tid;  // float4 index
    const float4* __restrict__ xin = (const float4*)x;
    fvec4* __restrict__ op = (fvec4*)out;

    // ---- issue prefetch of the first PRE float4s (saturate HBM from t0) ----
    float4 pre[PRE];
    #pragma unroll
    for (int it = 0; it < PRE; ++it) pre[it] = xin[base + (size_t)it * 256];

    // ---- per-block scale/bias (threads 0..63, c = tid) ----
    __shared__ float scb[2][C_];
    if (tid < C_) {
        const int myCls = cls[b];
        const int myDom = dom[b];
        float best = -1.0f;   // noise is uniform[0,1), any valid score beats -1
        int   bi   = -1;
        for (int j = 0; j < B_; ++j) {
            if (cls[j] == myCls && dom[j] != myDom) {
                float sc = select_noise[b * B_ + j];
                if (sc > best) { best = sc; bi = j; }
            }
        }
        const int idx = (bi < 0) ? b : bi;

        double s1 = 0.0, q1 = 0.0, s2 = 0.0, q2 = 0.0;
        for (int s = 0; s < S_; ++s) {
            s1 += (double)sumP[((size_t)b   * S_ + s) * C_ + tid];
            q1 += (double)sqP [((size_t)b   * S_ + s) * C_ + tid];
            s2 += (double)sumP[((size_t)idx * S_ + s) * C_ + tid];
            q2 += (double)sqP [((size_t)idx * S_ + s) * C_ + tid];
        }
        const double n = (double)N_;
        const float mu   = (float)(s1 / n);
        const float sig  = sqrtf((float)((q1 - s1 * s1 / n) / (n - 1.0)) + EPS_);
        const float mu2  = (float)(s2 / n);
        const float sig2 = sqrtf((float)((q2 - s2 * s2 / n) / (n - 1.0)) + EPS_);

        const float a = alpha_u[b] * ALPHA_MAX_;
        const float mu_mix  = mu  * a + mu2  * (1.0f - a);
        const float sig_mix = sig * a + sig2 * (1.0f - a);

        const float scale = sig_mix / sig;
        scb[0][tid] = scale;
        scb[1][tid] = mu_mix - mu * scale;
    }
    __syncthreads();

    const int c0 = (tid & 15) * 4;
    const float4 sc = make_float4(scb[0][c0], scb[0][c0+1], scb[0][c0+2], scb[0][c0+3]);
    const float4 bs = make_float4(scb[1][c0], scb[1][c0+1], scb[1][c0+2], scb[1][c0+3]);

    // ---- drain prefetched portion ----
    #pragma unroll
    for (int it = 0; it < PRE; ++it) {
        fvec4 o;
        o.x = fmaf(pre[it].x, sc.x, bs.x);
        o.y = fmaf(pre[it].y, sc.y, bs.y);
        o.z = fmaf(pre[it].z, sc.z, bs.z);
        o.w = fmaf(pre[it].w, sc.w, bs.w);
        __builtin_nontemporal_store(o, op + base + (size_t)it * 256);
    }
    // ---- stream the rest (24 iterations, unroll 8 for outstanding loads) ----
    #pragma unroll 8
    for (int it = PRE; it < 32; ++it) {
        const size_t g = base + (size_t)it * 256;
        float4 v = xin[g];
        fvec4 o;
        o.x = fmaf(v.x, sc.x, bs.x);
        o.y = fmaf(v.y, sc.y, bs.y);
        o.z = fmaf(v.z, sc.z, bs.z);
        o.w = fmaf(v.w, sc.w, bs.w);
        __builtin_nontemporal_store(o, op + g);
    }
}

// ---------------------------------------------------------------------------
extern "C" void kernel_launch(void* const* d_in, const int* in_sizes, int n_in,
                              void* d_out, int out_size, void* d_ws, size_t ws_size,
                              hipStream_t stream) {
    const float* x            = (const float*)d_in[0];
    const float* alpha_u      = (const float*)d_in[1];
    const float* select_noise = (const float*)d_in[2];
    const int*   dom          = (const int*)d_in[3];
    const int*   cls          = (const int*)d_in[4];
    float* out = (float*)d_out;

    // Workspace layout (floats): sumP[B_*S_*C_], sqP[B_*S_*C_]
    float* sumP = (float*)d_ws;
    float* sqP  = sumP + (size_t)B_ * S_ * C_;          // +65536

    // 1) partial stats: 1024 blocks x 256 threads
    stats_partial_kernel<<<B_ * S_, 256, 0, stream>>>(x, sumP, sqP);

    // 2) fused finalize + apply: 2048 blocks x 256 threads
    apply_fused_kernel<<<2048, 256, 0, stream>>>(
        x, sumP, sqP, alpha_u, select_noise, dom, cls, out);
}